// Round 4
// baseline (152.927 us; speedup 1.0000x reference)
//
#include <hip/hip_runtime.h>
#include <hip/hip_cooperative_groups.h>

namespace cg = cooperative_groups;

#define NN 768
#define NH 4
#define NEG 0.01f
#define RPB 8   // rows per phase-A block

__device__ __forceinline__ float leaky(float x) { return fmaxf(x, NEG * x); }

struct SharedA {
    float nrow[RPB][128];
    float hrow[RPB][128];
};

struct SharedB {
    float ulds[256];
    float w2l[4 * 256];
    float b2s[4];
    int   elist[NN];
    float sc[NH * NN];                 // head-major: sc[h*NN + e]
    unsigned long long masks[NN / 64];
    int   cnt[NN / 64];
};

// ---- Phase A: for 8 nodes: h = nodes@preW^T; U = h@W1a^T; Vb = h@W1b^T + b1;
//      out_h = nodes@postW^T ----
__device__ void phaseA(SharedA& s, int r0, int t,
                       const float* __restrict__ nodes,
                       const float* __restrict__ preW,
                       const float* __restrict__ postW,
                       const float* __restrict__ w1,
                       const float* __restrict__ b1,
                       float* __restrict__ U,
                       float* __restrict__ Vb,
                       float* __restrict__ out_h) {
    {   // stage 8 node rows: exactly 256 float4s
        const float4* src = (const float4*)(nodes + r0 * 128);
        float4* dst = (float4*)&s.nrow[0][0];
        dst[t] = src[t];
    }
    __syncthreads();

    {   // h_proj: d = t&127; group g = (t>>7)*4 handles rows g..g+3
        const int d = t & 127;
        const int g = (t >> 7) * 4;
        const float4* prow = (const float4*)(preW + d * 128);
        float a0 = 0.f, a1 = 0.f, a2 = 0.f, a3 = 0.f;
#pragma unroll
        for (int q = 0; q < 32; ++q) {
            float4 w = prow[q];
            int k = q * 4;
            a0 = fmaf(w.x, s.nrow[g+0][k],   a0); a1 = fmaf(w.x, s.nrow[g+1][k],   a1);
            a2 = fmaf(w.x, s.nrow[g+2][k],   a2); a3 = fmaf(w.x, s.nrow[g+3][k],   a3);
            a0 = fmaf(w.y, s.nrow[g+0][k+1], a0); a1 = fmaf(w.y, s.nrow[g+1][k+1], a1);
            a2 = fmaf(w.y, s.nrow[g+2][k+1], a2); a3 = fmaf(w.y, s.nrow[g+3][k+1], a3);
            a0 = fmaf(w.z, s.nrow[g+0][k+2], a0); a1 = fmaf(w.z, s.nrow[g+1][k+2], a1);
            a2 = fmaf(w.z, s.nrow[g+2][k+2], a2); a3 = fmaf(w.z, s.nrow[g+3][k+2], a3);
            a0 = fmaf(w.w, s.nrow[g+0][k+3], a0); a1 = fmaf(w.w, s.nrow[g+1][k+3], a1);
            a2 = fmaf(w.w, s.nrow[g+2][k+3], a2); a3 = fmaf(w.w, s.nrow[g+3][k+3], a3);
        }
        s.hrow[g+0][d] = a0; s.hrow[g+1][d] = a1;
        s.hrow[g+2][d] = a2; s.hrow[g+3][d] = a3;
    }
    __syncthreads();

    {   // U / Vb: thread t owns col t; w1 row t (256 floats)
        float u[RPB] = {}, v[RPB] = {};
        const float4* wrow = (const float4*)(w1 + t * 256);
#pragma unroll 4
        for (int q = 0; q < 32; ++q) {
            float4 w = wrow[q];
            int k = q * 4;
#pragma unroll
            for (int r = 0; r < RPB; ++r) {
                u[r] = fmaf(w.x, s.hrow[r][k],     u[r]);
                u[r] = fmaf(w.y, s.hrow[r][k + 1], u[r]);
                u[r] = fmaf(w.z, s.hrow[r][k + 2], u[r]);
                u[r] = fmaf(w.w, s.hrow[r][k + 3], u[r]);
            }
        }
#pragma unroll 4
        for (int q = 32; q < 64; ++q) {
            float4 w = wrow[q];
            int k = (q - 32) * 4;
#pragma unroll
            for (int r = 0; r < RPB; ++r) {
                v[r] = fmaf(w.x, s.hrow[r][k],     v[r]);
                v[r] = fmaf(w.y, s.hrow[r][k + 1], v[r]);
                v[r] = fmaf(w.z, s.hrow[r][k + 2], v[r]);
                v[r] = fmaf(w.w, s.hrow[r][k + 3], v[r]);
            }
        }
        float bb = b1[t];
#pragma unroll
        for (int r = 0; r < RPB; ++r) {
            U[(r0 + r) * 256 + t]  = u[r];
            Vb[(r0 + r) * 256 + t] = v[r] + bb;
        }
    }

    {   // out_h: thread t owns cols t, t+256; postW rows t, t+256
        float o0[RPB] = {}, o1[RPB] = {};
        const float4* p0 = (const float4*)(postW + t * 128);
        const float4* p1 = (const float4*)(postW + (t + 256) * 128);
#pragma unroll 4
        for (int q = 0; q < 32; ++q) {
            float4 wa = p0[q], wb = p1[q];
            int k = q * 4;
#pragma unroll
            for (int r = 0; r < RPB; ++r) {
                o0[r] = fmaf(wa.x, s.nrow[r][k],     o0[r]);
                o0[r] = fmaf(wa.y, s.nrow[r][k + 1], o0[r]);
                o0[r] = fmaf(wa.z, s.nrow[r][k + 2], o0[r]);
                o0[r] = fmaf(wa.w, s.nrow[r][k + 3], o0[r]);
                o1[r] = fmaf(wb.x, s.nrow[r][k],     o1[r]);
                o1[r] = fmaf(wb.y, s.nrow[r][k + 1], o1[r]);
                o1[r] = fmaf(wb.z, s.nrow[r][k + 2], o1[r]);
                o1[r] = fmaf(wb.w, s.nrow[r][k + 3], o1[r]);
            }
        }
#pragma unroll
        for (int r = 0; r < RPB; ++r) {
            out_h[(r0 + r) * 512 + t]       = o0[r];
            out_h[(r0 + r) * 512 + 256 + t] = o1[r];
        }
    }
}

// ---- Phase B: per destination row i: edges -> scores -> softmax -> aggregate ----
__device__ void phaseB(SharedB& s, int i, int t,
                       const float* __restrict__ adj,
                       const float* __restrict__ U,
                       const float* __restrict__ Vb,
                       const float* __restrict__ out_h,
                       const float* __restrict__ w2,
                       const float* __restrict__ b2,
                       float* __restrict__ out) {
    const int lane = t & 63, wv = t >> 6;

    s.ulds[t] = U[i * 256 + t];
#pragma unroll
    for (int q = 0; q < 4; ++q) s.w2l[q * 256 + t] = w2[q * 256 + t];
    if (t < 4) s.b2s[t] = b2[t];

    // ballot-based deterministic edge-list build (12 chunks of 64)
    for (int c = wv; c < NN / 64; c += 4) {
        float a = adj[i * NN + c * 64 + lane];
        unsigned long long m = __ballot(a != 0.0f);
        if (lane == 0) { s.masks[c] = m; s.cnt[c] = __popcll(m); }
    }
    __syncthreads();

    int ne = 0;
#pragma unroll
    for (int q = 0; q < NN / 64; ++q) ne += s.cnt[q];

    for (int c = wv; c < NN / 64; c += 4) {
        int off = 0;
        for (int q = 0; q < c; ++q) off += s.cnt[q];
        unsigned long long m = s.masks[c];
        if ((m >> lane) & 1ull) {
            int pos = off + __popcll(m & ((1ull << lane) - 1ull));
            s.elist[pos] = c * 64 + lane;
        }
    }
    __syncthreads();

    // scores: 4 edges per wave-iteration
    {
        const float4 uu  = ((const float4*)s.ulds)[lane];
        const float4 wh0 = ((const float4*)(s.w2l + 0 * 256))[lane];
        const float4 wh1 = ((const float4*)(s.w2l + 1 * 256))[lane];
        const float4 wh2 = ((const float4*)(s.w2l + 2 * 256))[lane];
        const float4 wh3 = ((const float4*)(s.w2l + 3 * 256))[lane];

        for (int e0 = wv * 4; e0 < ne; e0 += 16) {
            const int nb = min(4, ne - e0);
            float4 vv[4];
#pragma unroll
            for (int b = 0; b < 4; ++b) {
                if (b < nb) {
                    int j = s.elist[e0 + b];
                    vv[b] = *(const float4*)(Vb + j * 256 + lane * 4);
                } else {
                    vv[b] = make_float4(0.f, 0.f, 0.f, 0.f);
                }
            }
            float acc[4][4];
#pragma unroll
            for (int b = 0; b < 4; ++b) {
                float t0 = leaky(uu.x + vv[b].x);
                float t1 = leaky(uu.y + vv[b].y);
                float t2 = leaky(uu.z + vv[b].z);
                float t3 = leaky(uu.w + vv[b].w);
                acc[b][0] = fmaf(t0, wh0.x, fmaf(t1, wh0.y, fmaf(t2, wh0.z, t3 * wh0.w)));
                acc[b][1] = fmaf(t0, wh1.x, fmaf(t1, wh1.y, fmaf(t2, wh1.z, t3 * wh1.w)));
                acc[b][2] = fmaf(t0, wh2.x, fmaf(t1, wh2.y, fmaf(t2, wh2.z, t3 * wh2.w)));
                acc[b][3] = fmaf(t0, wh3.x, fmaf(t1, wh3.y, fmaf(t2, wh3.z, t3 * wh3.w)));
            }
#pragma unroll
            for (int off = 32; off; off >>= 1) {
#pragma unroll
                for (int b = 0; b < 4; ++b) {
#pragma unroll
                    for (int h = 0; h < 4; ++h)
                        acc[b][h] += __shfl_xor(acc[b][h], off);
                }
            }
            if (lane == 0) {
#pragma unroll
                for (int b = 0; b < 4; ++b) {
                    if (b < nb) {
#pragma unroll
                        for (int h = 0; h < 4; ++h)
                            s.sc[h * NN + e0 + b] = leaky(acc[b][h] + s.b2s[h]);
                    }
                }
            }
        }
    }
    __syncthreads();

    // masked softmax, one wave per head (head-major sc: conflict-free)
    {
        const int h = wv;
        float* srow = s.sc + h * NN;
        float m = -INFINITY;
        for (int e = lane; e < ne; e += 64) m = fmaxf(m, srow[e]);
#pragma unroll
        for (int off = 32; off; off >>= 1) m = fmaxf(m, __shfl_xor(m, off));
        float sum = 0.f;
        for (int e = lane; e < ne; e += 64) {
            float p = __expf(srow[e] - m);
            srow[e] = p;
            sum += p;
        }
#pragma unroll
        for (int off = 32; off; off >>= 1) sum += __shfl_xor(sum, off);
        float inv = 1.0f / sum;
        for (int e = lane; e < ne; e += 64) srow[e] *= inv;
    }
    __syncthreads();

    // aggregation: unroll 4, batch-issue 8 global loads per chunk
    {
        float acc0 = 0.f, acc1 = 0.f;
        const int h = t & 3;
        const float* srow = s.sc + h * NN;
        int e = 0;
        for (; e + 4 <= ne; e += 4) {
            int j0 = s.elist[e], j1 = s.elist[e + 1], j2 = s.elist[e + 2], j3 = s.elist[e + 3];
            float g0 = srow[e], g1 = srow[e + 1], g2 = srow[e + 2], g3 = srow[e + 3];
            float x0 = out_h[j0 * 512 + t],       x1 = out_h[j1 * 512 + t];
            float x2 = out_h[j2 * 512 + t],       x3 = out_h[j3 * 512 + t];
            float y0 = out_h[j0 * 512 + 256 + t], y1 = out_h[j1 * 512 + 256 + t];
            float y2 = out_h[j2 * 512 + 256 + t], y3 = out_h[j3 * 512 + 256 + t];
            acc0 = fmaf(g0, x0, fmaf(g1, x1, fmaf(g2, x2, fmaf(g3, x3, acc0))));
            acc1 = fmaf(g0, y0, fmaf(g1, y1, fmaf(g2, y2, fmaf(g3, y3, acc1))));
        }
        for (; e < ne; ++e) {
            int j = s.elist[e];
            float g = srow[e];
            acc0 = fmaf(g, out_h[j * 512 + t],       acc0);
            acc1 = fmaf(g, out_h[j * 512 + 256 + t], acc1);
        }
        out[i * 512 + t]       = acc0;
        out[i * 512 + 256 + t] = acc1;
    }
}

// ---- fused cooperative kernel: grid = 768, fully co-resident (3 blocks/CU) ----
__global__ __launch_bounds__(256, 3) void k_fused(const float* nodes, const float* adj,
                                                  const float* preW, const float* postW,
                                                  const float* w1, const float* b1,
                                                  const float* w2, const float* b2,
                                                  float* U, float* Vb, float* out_h,
                                                  float* out) {
    __shared__ SharedA sa;
    __shared__ SharedB sb;
    if (blockIdx.x < NN / RPB)
        phaseA(sa, blockIdx.x * RPB, threadIdx.x, nodes, preW, postW, w1, b1, U, Vb, out_h);
    cg::this_grid().sync();
    phaseB(sb, blockIdx.x, threadIdx.x, adj, U, Vb, out_h, w2, b2, out);
}

// ---- fallback pair (used if cooperative launch is unavailable) ----
__global__ __launch_bounds__(256) void k_pre2(const float* nodes, const float* preW,
                                              const float* postW, const float* w1,
                                              const float* b1, float* U, float* Vb,
                                              float* out_h) {
    __shared__ SharedA sa;
    phaseA(sa, blockIdx.x * RPB, threadIdx.x, nodes, preW, postW, w1, b1, U, Vb, out_h);
}

__global__ __launch_bounds__(256, 4) void k_attn2(const float* adj, const float* U,
                                                  const float* Vb, const float* out_h,
                                                  const float* w2, const float* b2,
                                                  float* out) {
    __shared__ SharedB sb;
    phaseB(sb, blockIdx.x, threadIdx.x, adj, U, Vb, out_h, w2, b2, out);
}

extern "C" void kernel_launch(void* const* d_in, const int* in_sizes, int n_in,
                              void* d_out, int out_size, void* d_ws, size_t ws_size,
                              hipStream_t stream) {
    const float* nodes = (const float*)d_in[0];
    const float* adj   = (const float*)d_in[1];
    const float* preW  = (const float*)d_in[2];
    const float* postW = (const float*)d_in[3];
    const float* w1    = (const float*)d_in[4];
    const float* b1    = (const float*)d_in[5];
    const float* w2    = (const float*)d_in[6];
    const float* b2    = (const float*)d_in[7];
    float* out = (float*)d_out;

    float* ws = (float*)d_ws;
    float* U     = ws;                 // 768*256
    float* Vb    = U + NN * 256;       // 768*256
    float* out_h = Vb + NN * 256;      // 768*512

    void* args[] = { (void*)&nodes, (void*)&adj, (void*)&preW, (void*)&postW,
                     (void*)&w1, (void*)&b1, (void*)&w2, (void*)&b2,
                     (void*)&U, (void*)&Vb, (void*)&out_h, (void*)&out };
    hipError_t err = hipLaunchCooperativeKernel((const void*)k_fused, dim3(NN), dim3(256),
                                                args, 0, stream);
    if (err != hipSuccess) {
        k_pre2<<<dim3(NN / RPB), dim3(256), 0, stream>>>(nodes, preW, postW, w1, b1, U, Vb, out_h);
        k_attn2<<<dim3(NN), dim3(256), 0, stream>>>(adj, U, Vb, out_h, w2, b2, out);
    }
}

// Round 5
// 141.491 us; speedup vs baseline: 1.0808x; 1.0808x over previous
//
#include <hip/hip_runtime.h>

#define NN 768
#define WD 256      // ATTN_WIDTH
#define NH 4
#define NEG 0.01f
#define RPB 4       // rows (nodes) per block in k_pre

__device__ __forceinline__ float leaky(float x) { return fmaxf(x, NEG * x); }

// ---- K_pre: per 4 nodes: h = nodes@preW^T; U = h@W1a^T; Vb = h@W1b^T + b1;
//      out_h = nodes@postW^T. (identical to round 3) ----
__global__ __launch_bounds__(256) void k_pre(const float* __restrict__ nodes,
                                             const float* __restrict__ preW,
                                             const float* __restrict__ postW,
                                             const float* __restrict__ w1,
                                             const float* __restrict__ b1,
                                             float* __restrict__ U,
                                             float* __restrict__ Vb,
                                             float* __restrict__ out_h) {
    __shared__ float nrow[RPB][128];
    __shared__ float hrow[RPB][128];
    const int r0 = blockIdx.x * RPB;
    const int t = threadIdx.x;

    {
        const float4* src = (const float4*)(nodes + r0 * 128);
        float4* dst = (float4*)&nrow[0][0];
        for (int idx = t; idx < RPB * 32; idx += 256) dst[idx] = src[idx];
    }
    __syncthreads();

    {
        const int d = t & 127;
        const int ra = (t >> 7) * 2, rb = ra + 1;
        const float4* prow = (const float4*)(preW + d * 128);
        float a0 = 0.f, a1 = 0.f;
#pragma unroll
        for (int q = 0; q < 32; ++q) {
            float4 w = prow[q];
            int k = q * 4;
            a0 = fmaf(w.x, nrow[ra][k],     a0); a1 = fmaf(w.x, nrow[rb][k],     a1);
            a0 = fmaf(w.y, nrow[ra][k + 1], a0); a1 = fmaf(w.y, nrow[rb][k + 1], a1);
            a0 = fmaf(w.z, nrow[ra][k + 2], a0); a1 = fmaf(w.z, nrow[rb][k + 2], a1);
            a0 = fmaf(w.w, nrow[ra][k + 3], a0); a1 = fmaf(w.w, nrow[rb][k + 3], a1);
        }
        hrow[ra][d] = a0;
        hrow[rb][d] = a1;
    }
    __syncthreads();

    {
        float u[RPB] = {}, v[RPB] = {};
        const float4* wrow = (const float4*)(w1 + t * 256);
#pragma unroll 8
        for (int q = 0; q < 32; ++q) {
            float4 w = wrow[q];
            int k = q * 4;
#pragma unroll
            for (int r = 0; r < RPB; ++r) {
                u[r] = fmaf(w.x, hrow[r][k],     u[r]);
                u[r] = fmaf(w.y, hrow[r][k + 1], u[r]);
                u[r] = fmaf(w.z, hrow[r][k + 2], u[r]);
                u[r] = fmaf(w.w, hrow[r][k + 3], u[r]);
            }
        }
#pragma unroll 8
        for (int q = 32; q < 64; ++q) {
            float4 w = wrow[q];
            int k = (q - 32) * 4;
#pragma unroll
            for (int r = 0; r < RPB; ++r) {
                v[r] = fmaf(w.x, hrow[r][k],     v[r]);
                v[r] = fmaf(w.y, hrow[r][k + 1], v[r]);
                v[r] = fmaf(w.z, hrow[r][k + 2], v[r]);
                v[r] = fmaf(w.w, hrow[r][k + 3], v[r]);
            }
        }
        float bb = b1[t];
#pragma unroll
        for (int r = 0; r < RPB; ++r) {
            U[(r0 + r) * 256 + t]  = u[r];
            Vb[(r0 + r) * 256 + t] = v[r] + bb;
        }
    }

    {
        float o0[RPB] = {}, o1[RPB] = {};
        const float4* p0 = (const float4*)(postW + t * 128);
        const float4* p1 = (const float4*)(postW + (t + 256) * 128);
#pragma unroll 8
        for (int q = 0; q < 32; ++q) {
            float4 wa = p0[q], wb = p1[q];
            int k = q * 4;
#pragma unroll
            for (int r = 0; r < RPB; ++r) {
                o0[r] = fmaf(wa.x, nrow[r][k],     o0[r]);
                o0[r] = fmaf(wa.y, nrow[r][k + 1], o0[r]);
                o0[r] = fmaf(wa.z, nrow[r][k + 2], o0[r]);
                o0[r] = fmaf(wa.w, nrow[r][k + 3], o0[r]);
                o1[r] = fmaf(wb.x, nrow[r][k],     o1[r]);
                o1[r] = fmaf(wb.y, nrow[r][k + 1], o1[r]);
                o1[r] = fmaf(wb.z, nrow[r][k + 2], o1[r]);
                o1[r] = fmaf(wb.w, nrow[r][k + 3], o1[r]);
            }
        }
#pragma unroll
        for (int r = 0; r < RPB; ++r) {
            out_h[(r0 + r) * 512 + t]       = o0[r];
            out_h[(r0 + r) * 512 + 256 + t] = o1[r];
        }
    }
}

// ---- K_attn: identical to round 3 ----
__global__ __launch_bounds__(256, 4) void k_attn(const float* __restrict__ adj,
                                                 const float* __restrict__ U,
                                                 const float* __restrict__ Vb,
                                                 const float* __restrict__ out_h,
                                                 const float* __restrict__ w2,
                                                 const float* __restrict__ b2,
                                                 float* __restrict__ out) {
    __shared__ float ulds[256];
    __shared__ float w2l[4 * 256];
    __shared__ float b2s[4];
    __shared__ int elist[NN];
    __shared__ float sc[NH * NN];               // head-major: sc[h*NN + e]
    __shared__ unsigned long long masks[NN / 64];
    __shared__ int cnt[NN / 64];

    const int i = blockIdx.x, t = threadIdx.x;
    const int lane = t & 63, wv = t >> 6;

    ulds[t] = U[i * 256 + t];
#pragma unroll
    for (int q = 0; q < 4; ++q) w2l[q * 256 + t] = w2[q * 256 + t];
    if (t < 4) b2s[t] = b2[t];

    for (int c = wv; c < NN / 64; c += 4) {
        float a = adj[i * NN + c * 64 + lane];
        unsigned long long m = __ballot(a != 0.0f);
        if (lane == 0) { masks[c] = m; cnt[c] = __popcll(m); }
    }
    __syncthreads();

    int ne = 0;
#pragma unroll
    for (int q = 0; q < NN / 64; ++q) ne += cnt[q];

    for (int c = wv; c < NN / 64; c += 4) {
        int off = 0;
        for (int q = 0; q < c; ++q) off += cnt[q];
        unsigned long long m = masks[c];
        if ((m >> lane) & 1ull) {
            int pos = off + __popcll(m & ((1ull << lane) - 1ull));
            elist[pos] = c * 64 + lane;
        }
    }
    __syncthreads();

    {
        const float4 uu  = ((const float4*)ulds)[lane];
        const float4 wh0 = ((const float4*)(w2l + 0 * 256))[lane];
        const float4 wh1 = ((const float4*)(w2l + 1 * 256))[lane];
        const float4 wh2 = ((const float4*)(w2l + 2 * 256))[lane];
        const float4 wh3 = ((const float4*)(w2l + 3 * 256))[lane];

        for (int e0 = wv * 4; e0 < ne; e0 += 16) {
            const int nb = min(4, ne - e0);
            float4 vv[4];
#pragma unroll
            for (int b = 0; b < 4; ++b) {
                if (b < nb) {
                    int j = elist[e0 + b];
                    vv[b] = *(const float4*)(Vb + j * 256 + lane * 4);
                } else {
                    vv[b] = make_float4(0.f, 0.f, 0.f, 0.f);
                }
            }
            float acc[4][4];
#pragma unroll
            for (int b = 0; b < 4; ++b) {
                float t0 = leaky(uu.x + vv[b].x);
                float t1 = leaky(uu.y + vv[b].y);
                float t2 = leaky(uu.z + vv[b].z);
                float t3 = leaky(uu.w + vv[b].w);
                acc[b][0] = fmaf(t0, wh0.x, fmaf(t1, wh0.y, fmaf(t2, wh0.z, t3 * wh0.w)));
                acc[b][1] = fmaf(t0, wh1.x, fmaf(t1, wh1.y, fmaf(t2, wh1.z, t3 * wh1.w)));
                acc[b][2] = fmaf(t0, wh2.x, fmaf(t1, wh2.y, fmaf(t2, wh2.z, t3 * wh2.w)));
                acc[b][3] = fmaf(t0, wh3.x, fmaf(t1, wh3.y, fmaf(t2, wh3.z, t3 * wh3.w)));
            }
#pragma unroll
            for (int off = 32; off; off >>= 1) {
#pragma unroll
                for (int b = 0; b < 4; ++b) {
#pragma unroll
                    for (int h = 0; h < 4; ++h)
                        acc[b][h] += __shfl_xor(acc[b][h], off);
                }
            }
            if (lane == 0) {
#pragma unroll
                for (int b = 0; b < 4; ++b) {
                    if (b < nb) {
#pragma unroll
                        for (int h = 0; h < 4; ++h)
                            sc[h * NN + e0 + b] = leaky(acc[b][h] + b2s[h]);
                    }
                }
            }
        }
    }
    __syncthreads();

    {
        const int h = wv;
        float* srow = sc + h * NN;
        float m = -INFINITY;
        for (int e = lane; e < ne; e += 64) m = fmaxf(m, srow[e]);
#pragma unroll
        for (int off = 32; off; off >>= 1) m = fmaxf(m, __shfl_xor(m, off));
        float s = 0.f;
        for (int e = lane; e < ne; e += 64) {
            float p = __expf(srow[e] - m);
            srow[e] = p;
            s += p;
        }
#pragma unroll
        for (int off = 32; off; off >>= 1) s += __shfl_xor(s, off);
        float inv = 1.0f / s;
        for (int e = lane; e < ne; e += 64) srow[e] *= inv;
    }
    __syncthreads();

    {
        float acc0 = 0.f, acc1 = 0.f;
        const int h = t & 3;
        const float* srow = sc + h * NN;
        int e = 0;
        for (; e + 4 <= ne; e += 4) {
            int j0 = elist[e], j1 = elist[e + 1], j2 = elist[e + 2], j3 = elist[e + 3];
            float g0 = srow[e], g1 = srow[e + 1], g2 = srow[e + 2], g3 = srow[e + 3];
            float x0 = out_h[j0 * 512 + t],       x1 = out_h[j1 * 512 + t];
            float x2 = out_h[j2 * 512 + t],       x3 = out_h[j3 * 512 + t];
            float y0 = out_h[j0 * 512 + 256 + t], y1 = out_h[j1 * 512 + 256 + t];
            float y2 = out_h[j2 * 512 + 256 + t], y3 = out_h[j3 * 512 + 256 + t];
            acc0 = fmaf(g0, x0, fmaf(g1, x1, fmaf(g2, x2, fmaf(g3, x3, acc0))));
            acc1 = fmaf(g0, y0, fmaf(g1, y1, fmaf(g2, y2, fmaf(g3, y3, acc1))));
        }
        for (; e < ne; ++e) {
            int j = elist[e];
            float g = srow[e];
            acc0 = fmaf(g, out_h[j * 512 + t],       acc0);
            acc1 = fmaf(g, out_h[j * 512 + 256 + t], acc1);
        }
        out[i * 512 + t]       = acc0;
        out[i * 512 + 256 + t] = acc1;
    }
}

extern "C" void kernel_launch(void* const* d_in, const int* in_sizes, int n_in,
                              void* d_out, int out_size, void* d_ws, size_t ws_size,
                              hipStream_t stream) {
    const float* nodes = (const float*)d_in[0];
    const float* adj   = (const float*)d_in[1];
    const float* preW  = (const float*)d_in[2];
    const float* postW = (const float*)d_in[3];
    const float* w1    = (const float*)d_in[4];
    const float* b1    = (const float*)d_in[5];
    const float* w2    = (const float*)d_in[6];
    const float* b2    = (const float*)d_in[7];
    float* out = (float*)d_out;

    float* ws = (float*)d_ws;
    float* U     = ws;                 // 768*256
    float* Vb    = U + NN * 256;       // 768*256
    float* out_h = Vb + NN * 256;      // 768*512

    // Decomposition experiment: run the identical dependent pair 3x.
    // dur = fixed + 3*(kp + ka); round-3 gave fixed + (kp + ka) = 49.7 us.
    for (int rep = 0; rep < 3; ++rep) {
        k_pre<<<dim3(NN / RPB), dim3(256), 0, stream>>>(nodes, preW, postW, w1, b1, U, Vb, out_h);
        k_attn<<<dim3(NN), dim3(256), 0, stream>>>(adj, U, Vb, out_h, w2, b2, out);
    }
}

// Round 6
// 71.665 us; speedup vs baseline: 2.1339x; 1.9743x over previous
//
#include <hip/hip_runtime.h>

#define NN 768
#define NH 4
#define NEG 0.01f
#define RPB 4
#define NPROD (NN / RPB)        // 192 producer blocks
#define MAGICF 0x13579BDFu

__device__ __forceinline__ float leaky(float x) { return fmaxf(x, NEG * x); }

union SharedU {
    struct {                      // phase A (producers): 4 KB
        float nrow[RPB][128];
        float hrow[RPB][128];
    } a;
    struct {                      // phase B: ~20.6 KB
        float ulds[256];
        float w2l[4 * 256];
        float b2s[4];
        int   elist[NN];
        float sc[NH * NN];        // head-major: sc[h*NN + e]
        unsigned long long masks[NN / 64];
        int   cnt[NN / 64];
    } b;
};

__global__ __launch_bounds__(256, 3) void k_gat(
        const float* __restrict__ nodes, const float* __restrict__ adj,
        const float* __restrict__ preW,  const float* __restrict__ postW,
        const float* __restrict__ w1,    const float* __restrict__ b1,
        const float* __restrict__ w2,    const float* __restrict__ b2,
        float* __restrict__ U, float* __restrict__ Vb,
        float* __restrict__ out_h, unsigned* __restrict__ flags,
        float* __restrict__ out)
{
    __shared__ SharedU s;
    const int t = threadIdx.x;
    const int bid = blockIdx.x;

    // ================= phase A: producer blocks 0..191, rows 4b..4b+3 =================
    if (bid < NPROD) {
        const int r0 = bid * RPB;
        {
            const float4* src = (const float4*)(nodes + r0 * 128);
            float4* dst = (float4*)&s.a.nrow[0][0];
            for (int idx = t; idx < RPB * 32; idx += 256) dst[idx] = src[idx];
        }
        __syncthreads();
        {   // h_proj
            const int d = t & 127;
            const int ra = (t >> 7) * 2, rb = ra + 1;
            const float4* prow = (const float4*)(preW + d * 128);
            float a0 = 0.f, a1 = 0.f;
#pragma unroll
            for (int q = 0; q < 32; ++q) {
                float4 w = prow[q];
                int k = q * 4;
                a0 = fmaf(w.x, s.a.nrow[ra][k],   a0); a1 = fmaf(w.x, s.a.nrow[rb][k],   a1);
                a0 = fmaf(w.y, s.a.nrow[ra][k+1], a0); a1 = fmaf(w.y, s.a.nrow[rb][k+1], a1);
                a0 = fmaf(w.z, s.a.nrow[ra][k+2], a0); a1 = fmaf(w.z, s.a.nrow[rb][k+2], a1);
                a0 = fmaf(w.w, s.a.nrow[ra][k+3], a0); a1 = fmaf(w.w, s.a.nrow[rb][k+3], a1);
            }
            s.a.hrow[ra][d] = a0;
            s.a.hrow[rb][d] = a1;
        }
        __syncthreads();
        {   // U / Vb (nontemporal stores -> memory, no L2 flush needed)
            float u[RPB] = {}, v[RPB] = {};
            const float4* wrow = (const float4*)(w1 + t * 256);
#pragma unroll 8
            for (int q = 0; q < 32; ++q) {
                float4 w = wrow[q];
                int k = q * 4;
#pragma unroll
                for (int r = 0; r < RPB; ++r) {
                    u[r] = fmaf(w.x, s.a.hrow[r][k],   u[r]);
                    u[r] = fmaf(w.y, s.a.hrow[r][k+1], u[r]);
                    u[r] = fmaf(w.z, s.a.hrow[r][k+2], u[r]);
                    u[r] = fmaf(w.w, s.a.hrow[r][k+3], u[r]);
                }
            }
#pragma unroll 8
            for (int q = 32; q < 64; ++q) {
                float4 w = wrow[q];
                int k = (q - 32) * 4;
#pragma unroll
                for (int r = 0; r < RPB; ++r) {
                    v[r] = fmaf(w.x, s.a.hrow[r][k],   v[r]);
                    v[r] = fmaf(w.y, s.a.hrow[r][k+1], v[r]);
                    v[r] = fmaf(w.z, s.a.hrow[r][k+2], v[r]);
                    v[r] = fmaf(w.w, s.a.hrow[r][k+3], v[r]);
                }
            }
            float bb = b1[t];
#pragma unroll
            for (int r = 0; r < RPB; ++r) {
                __builtin_nontemporal_store(u[r],      &U[(r0 + r) * 256 + t]);
                __builtin_nontemporal_store(v[r] + bb, &Vb[(r0 + r) * 256 + t]);
            }
        }
        {   // out_h
            float o0[RPB] = {}, o1[RPB] = {};
            const float4* p0 = (const float4*)(postW + t * 128);
            const float4* p1 = (const float4*)(postW + (t + 256) * 128);
#pragma unroll 8
            for (int q = 0; q < 32; ++q) {
                float4 wa = p0[q], wb = p1[q];
                int k = q * 4;
#pragma unroll
                for (int r = 0; r < RPB; ++r) {
                    o0[r] = fmaf(wa.x, s.a.nrow[r][k],   o0[r]);
                    o0[r] = fmaf(wa.y, s.a.nrow[r][k+1], o0[r]);
                    o0[r] = fmaf(wa.z, s.a.nrow[r][k+2], o0[r]);
                    o0[r] = fmaf(wa.w, s.a.nrow[r][k+3], o0[r]);
                    o1[r] = fmaf(wb.x, s.a.nrow[r][k],   o1[r]);
                    o1[r] = fmaf(wb.y, s.a.nrow[r][k+1], o1[r]);
                    o1[r] = fmaf(wb.z, s.a.nrow[r][k+2], o1[r]);
                    o1[r] = fmaf(wb.w, s.a.nrow[r][k+3], o1[r]);
                }
            }
#pragma unroll
            for (int r = 0; r < RPB; ++r) {
                __builtin_nontemporal_store(o0[r], &out_h[(r0 + r) * 512 + t]);
                __builtin_nontemporal_store(o1[r], &out_h[(r0 + r) * 512 + 256 + t]);
            }
        }
        __threadfence();          // drain this thread's stores (vmcnt)
        __syncthreads();          // all threads' stores complete
        if (t == 0) atomicExch(&flags[bid], MAGICF);   // device-scope publish
    }

    // ================= device-wide barrier on the 192 producer flags =================
    if (t < NPROD) {
        while (__hip_atomic_load(&flags[t], __ATOMIC_RELAXED,
                                 __HIP_MEMORY_SCOPE_AGENT) != MAGICF)
            __builtin_amdgcn_s_sleep(8);
    }
    __syncthreads();

    // ================= phase B: one block per destination row =================
    const int i = bid;
    const int lane = t & 63, wv = t >> 6;

    s.b.ulds[t] = U[i * 256 + t];
#pragma unroll
    for (int q = 0; q < 4; ++q) s.b.w2l[q * 256 + t] = w2[q * 256 + t];
    if (t < 4) s.b.b2s[t] = b2[t];

    for (int c = wv; c < NN / 64; c += 4) {
        float a = adj[i * NN + c * 64 + lane];
        unsigned long long m = __ballot(a != 0.0f);
        if (lane == 0) { s.b.masks[c] = m; s.b.cnt[c] = __popcll(m); }
    }
    __syncthreads();

    int ne = 0;
#pragma unroll
    for (int q = 0; q < NN / 64; ++q) ne += s.b.cnt[q];

    for (int c = wv; c < NN / 64; c += 4) {
        int off = 0;
        for (int q = 0; q < c; ++q) off += s.b.cnt[q];
        unsigned long long m = s.b.masks[c];
        if ((m >> lane) & 1ull) {
            int pos = off + __popcll(m & ((1ull << lane) - 1ull));
            s.b.elist[pos] = c * 64 + lane;
        }
    }
    __syncthreads();

    {   // scores: 4 edges per wave-iteration
        const float4 uu  = ((const float4*)s.b.ulds)[lane];
        const float4 wh0 = ((const float4*)(s.b.w2l + 0 * 256))[lane];
        const float4 wh1 = ((const float4*)(s.b.w2l + 1 * 256))[lane];
        const float4 wh2 = ((const float4*)(s.b.w2l + 2 * 256))[lane];
        const float4 wh3 = ((const float4*)(s.b.w2l + 3 * 256))[lane];

        for (int e0 = wv * 4; e0 < ne; e0 += 16) {
            const int nb = min(4, ne - e0);
            float4 vv[4];
#pragma unroll
            for (int b = 0; b < 4; ++b) {
                if (b < nb) {
                    int j = s.b.elist[e0 + b];
                    vv[b] = *(const float4*)(Vb + j * 256 + lane * 4);
                } else {
                    vv[b] = make_float4(0.f, 0.f, 0.f, 0.f);
                }
            }
            float acc[4][4];
#pragma unroll
            for (int b = 0; b < 4; ++b) {
                float t0 = leaky(uu.x + vv[b].x);
                float t1 = leaky(uu.y + vv[b].y);
                float t2 = leaky(uu.z + vv[b].z);
                float t3 = leaky(uu.w + vv[b].w);
                acc[b][0] = fmaf(t0, wh0.x, fmaf(t1, wh0.y, fmaf(t2, wh0.z, t3 * wh0.w)));
                acc[b][1] = fmaf(t0, wh1.x, fmaf(t1, wh1.y, fmaf(t2, wh1.z, t3 * wh1.w)));
                acc[b][2] = fmaf(t0, wh2.x, fmaf(t1, wh2.y, fmaf(t2, wh2.z, t3 * wh2.w)));
                acc[b][3] = fmaf(t0, wh3.x, fmaf(t1, wh3.y, fmaf(t2, wh3.z, t3 * wh3.w)));
            }
#pragma unroll
            for (int off = 32; off; off >>= 1) {
#pragma unroll
                for (int b = 0; b < 4; ++b) {
#pragma unroll
                    for (int h = 0; h < 4; ++h)
                        acc[b][h] += __shfl_xor(acc[b][h], off);
                }
            }
            if (lane == 0) {
#pragma unroll
                for (int b = 0; b < 4; ++b) {
                    if (b < nb) {
#pragma unroll
                        for (int h = 0; h < 4; ++h)
                            s.b.sc[h * NN + e0 + b] = leaky(acc[b][h] + s.b.b2s[h]);
                    }
                }
            }
        }
    }
    __syncthreads();

    {   // masked softmax, one wave per head
        const int h = wv;
        float* srow = s.b.sc + h * NN;
        float m = -INFINITY;
        for (int e = lane; e < ne; e += 64) m = fmaxf(m, srow[e]);
#pragma unroll
        for (int off = 32; off; off >>= 1) m = fmaxf(m, __shfl_xor(m, off));
        float sum = 0.f;
        for (int e = lane; e < ne; e += 64) {
            float p = __expf(srow[e] - m);
            srow[e] = p;
            sum += p;
        }
#pragma unroll
        for (int off = 32; off; off >>= 1) sum += __shfl_xor(sum, off);
        float inv = 1.0f / sum;
        for (int e = lane; e < ne; e += 64) srow[e] *= inv;
    }
    __syncthreads();

    {   // aggregation
        float acc0 = 0.f, acc1 = 0.f;
        const int h = t & 3;
        const float* srow = s.b.sc + h * NN;
        int e = 0;
        for (; e + 4 <= ne; e += 4) {
            int j0 = s.b.elist[e], j1 = s.b.elist[e + 1];
            int j2 = s.b.elist[e + 2], j3 = s.b.elist[e + 3];
            float g0 = srow[e], g1 = srow[e + 1], g2 = srow[e + 2], g3 = srow[e + 3];
            float x0 = out_h[j0 * 512 + t],       x1 = out_h[j1 * 512 + t];
            float x2 = out_h[j2 * 512 + t],       x3 = out_h[j3 * 512 + t];
            float y0 = out_h[j0 * 512 + 256 + t], y1 = out_h[j1 * 512 + 256 + t];
            float y2 = out_h[j2 * 512 + 256 + t], y3 = out_h[j3 * 512 + 256 + t];
            acc0 = fmaf(g0, x0, fmaf(g1, x1, fmaf(g2, x2, fmaf(g3, x3, acc0))));
            acc1 = fmaf(g0, y0, fmaf(g1, y1, fmaf(g2, y2, fmaf(g3, y3, acc1))));
        }
        for (; e < ne; ++e) {
            int j = s.b.elist[e];
            float g = srow[e];
            acc0 = fmaf(g, out_h[j * 512 + t],       acc0);
            acc1 = fmaf(g, out_h[j * 512 + 256 + t], acc1);
        }
        out[i * 512 + t]       = acc0;
        out[i * 512 + 256 + t] = acc1;
    }
}

extern "C" void kernel_launch(void* const* d_in, const int* in_sizes, int n_in,
                              void* d_out, int out_size, void* d_ws, size_t ws_size,
                              hipStream_t stream) {
    const float* nodes = (const float*)d_in[0];
    const float* adj   = (const float*)d_in[1];
    const float* preW  = (const float*)d_in[2];
    const float* postW = (const float*)d_in[3];
    const float* w1    = (const float*)d_in[4];
    const float* b1    = (const float*)d_in[5];
    const float* w2    = (const float*)d_in[6];
    const float* b2    = (const float*)d_in[7];
    float* out = (float*)d_out;

    float* ws = (float*)d_ws;
    float* U     = ws;                         // 768*256
    float* Vb    = U + NN * 256;               // 768*256
    float* out_h = Vb + NN * 256;              // 768*512
    unsigned* flags = (unsigned*)(out_h + NN * 512);   // 192 words

    k_gat<<<dim3(NN), dim3(256), 0, stream>>>(nodes, adj, preW, postW, w1, b1,
                                              w2, b2, U, Vb, out_h, flags, out);
}